// Round 8
// baseline (200.932 us; speedup 1.0000x reference)
//
#include <hip/hip_runtime.h>
#include <hip/hip_bf16.h>
#include <stdint.h>

// Problem constants
#define B_DIM 8
#define S_DIM 4096
#define I_DIM 256
#define M_DIM (B_DIM * S_DIM)   // 32768 rows
#define N_DIM 1536              // 6*OUT gate columns
#define K_DIM 512               // WINDOW*I

// GEMM tiling
#define TM 128
#define TN 128
#define BK 64
#define LT_STRIDE 136           // fp16 m-stride of epilogue transpose chunk (pad 8)

#define NX4 ((M_DIM * I_DIM) / 4)
#define NW4 ((N_DIM * K_DIM) / 4)

typedef __attribute__((ext_vector_type(8))) short bf16x8;
typedef __attribute__((ext_vector_type(4))) float f32x4;
typedef _Float16 h2 __attribute__((ext_vector_type(2)));
typedef _Float16 h4 __attribute__((ext_vector_type(4)));
typedef _Float16 h8 __attribute__((ext_vector_type(8)));

typedef const void __attribute__((address_space(1)))* gas_ptr;
typedef void __attribute__((address_space(3)))* las_ptr;

__device__ __forceinline__ void gload_lds16(const void* g, void* l) {
    __builtin_amdgcn_global_load_lds((gas_ptr)(uintptr_t)g, (las_ptr)(uintptr_t)l, 16, 0, 0);
}

__device__ __forceinline__ float fast_sigmoid(float x) {
    return 1.0f / (1.0f + __expf(-x));
}
__device__ __forceinline__ float fast_tanh(float x) {
    float ax = fabsf(x);
    float e = __expf(-2.0f * ax);
    float t = (1.0f - e) / (1.0f + e);
    return copysignf(t, x);
}

__device__ __forceinline__ unsigned short f2bf(float f) {
    uint32_t u = __float_as_uint(f);
    uint32_t r = (u + 0x7FFFu + ((u >> 16) & 1u)) >> 16;
    return (unsigned short)r;
}

// ---------------------------------------------------------------------------
// Single conversion kernel: x -> bf16, W -> bf16, zero page.
// ---------------------------------------------------------------------------
__global__ __launch_bounds__(256)
void cvt_all(const float* __restrict__ x, const float* __restrict__ W,
             unsigned short* __restrict__ xb, unsigned short* __restrict__ Wb,
             unsigned short* __restrict__ zp)
{
    int i = blockIdx.x * 256 + threadIdx.x;
    if (blockIdx.x == 0 && threadIdx.x < 64) zp[threadIdx.x] = 0;
    if (i < NX4) {
        float4 v = ((const float4*)x)[i];
        ushort4 o;
        o.x = f2bf(v.x); o.y = f2bf(v.y); o.z = f2bf(v.z); o.w = f2bf(v.w);
        ((ushort4*)xb)[i] = o;
    } else if (i < NX4 + NW4) {
        int j = i - NX4;
        float4 v = ((const float4*)W)[j];
        ushort4 o;
        o.x = f2bf(v.x); o.y = f2bf(v.y); o.z = f2bf(v.z); o.w = f2bf(v.w);
        ((ushort4*)Wb)[j] = o;
    }
}

// ---------------------------------------------------------------------------
// Windowed GEMM + bias -> PRE-ACTIVATION fp16, TRANSPOSED gT[col][m].
// Epilogue: LDS transpose in TWO 64-column halves, reusing the 32 KB staging
// LDS exactly (17.4 KB chunk) -> LDS stays 32768 B -> 5 blocks/CU (R7's
// 34.8 KB cost a block of occupancy).
// A[m][k] = (k<256) ? x[b, s-1, k] (0 if s==0) : x[b, s, k-256]
// ---------------------------------------------------------------------------
__global__ __launch_bounds__(256, 2)
void qrnn_gemm(const __hip_bfloat16* __restrict__ x,
               const __hip_bfloat16* __restrict__ W,
               const float* __restrict__ bias,
               _Float16* __restrict__ gT,
               const __hip_bfloat16* __restrict__ zeroPage)
{
    __shared__ __hip_bfloat16 smem[TM * BK + TN * BK];   // 32 KB
    __hip_bfloat16* lA = smem;
    __hip_bfloat16* lB = smem + TM * BK;
    _Float16* tsp = (_Float16*)smem;                     // transpose chunk alias

    const int tid = threadIdx.x;
    const int w = tid >> 6;
    const int l = tid & 63;

    const int tileM = blockIdx.x & 255;
    const int tileN = blockIdx.x >> 8;
    const int m0 = tileM * TM;
    const int n0 = tileN * TN;
    const int bIdx = m0 >> 12;
    const int sBase = m0 & 4095;

    const int c8 = (l & 7) ^ ((l >> 3) & 7);
    const int rowInP = w * 8 + (l >> 3);

    const int la = l & 15, lq = l >> 4;
    const int wm = w >> 1, wn = w & 1;

    f32x4 acc[4][4] = {};

    for (int kt = 0; kt < K_DIM / BK; ++kt) {
        __syncthreads();
        const int kcol = kt * 64 + c8 * 8;
#pragma unroll
        for (int p = 0; p < 4; ++p) {
            const int r = p * 32 + rowInP;
            const int srow = sBase + r;
            const __hip_bfloat16* srcA;
            if (kcol < 256) {
                srcA = (srow == 0) ? zeroPage
                     : x + ((size_t)((bIdx << 12) + srow - 1) * 256 + kcol);
            } else {
                srcA = x + ((size_t)((bIdx << 12) + srow) * 256 + (kcol - 256));
            }
            gload_lds16(srcA, &lA[p * 2048 + w * 512]);
            gload_lds16(W + ((size_t)(n0 + r) * 512 + kcol), &lB[p * 2048 + w * 512]);
        }
        __syncthreads();

#pragma unroll
        for (int kk = 0; kk < 2; ++kk) {
            bf16x8 af[4], bfr[4];
#pragma unroll
            for (int i = 0; i < 4; ++i) {
                const int ra = wm * 64 + i * 16 + la;
                const int ch = (kk * 4 + lq) ^ (ra & 7);
                af[i] = *(const bf16x8*)&lA[ra * 64 + ch * 8];
            }
#pragma unroll
            for (int j = 0; j < 4; ++j) {
                const int rb = wn * 64 + j * 16 + la;
                const int ch = (kk * 4 + lq) ^ (rb & 7);
                bfr[j] = *(const bf16x8*)&lB[rb * 64 + ch * 8];
            }
#pragma unroll
            for (int i = 0; i < 4; ++i)
#pragma unroll
                for (int j = 0; j < 4; ++j)
                    acc[i][j] = __builtin_amdgcn_mfma_f32_16x16x32_bf16(
                        af[i], bfr[j], acc[i][j], 0, 0, 0);
        }
    }

    // ---- epilogue: two 64-column halves through a 17.4 KB LDS chunk ----
    const int grp = tid >> 3;    // 0..31
    const int ln8 = tid & 7;
#pragma unroll
    for (int half = 0; half < 2; ++half) {
        __syncthreads();   // protect LDS (staging for half 0, prev chunk for half 1)
        if (wn == half) {
#pragma unroll
            for (int j = 0; j < 4; ++j) {
                const int colL = j * 16 + la;                // 0..63 in this half
                const float bv = bias[n0 + half * 64 + colL];
                _Float16* base = tsp + colL * LT_STRIDE + wm * 64 + lq * 4;
#pragma unroll
                for (int i = 0; i < 4; ++i) {
                    h4 hv;
#pragma unroll
                    for (int rr = 0; rr < 4; ++rr)
                        hv[rr] = (_Float16)(acc[i][j][rr] + bv);
                    *(h4*)(base + i * 16) = hv;
                }
            }
        }
        __syncthreads();
        // all 256 threads stream: 8 consecutive lanes = one column's 128B run
#pragma unroll
        for (int it = 0; it < 4; ++it) {
            const int colL = grp + 32 * (it & 1);            // 0..63
            const int mseg = ln8 + 8 * (it >> 1);            // 0..15
            h8 v = *(const h8*)(tsp + colL * LT_STRIDE + mseg * 8);
            *(h8*)(gT + (size_t)(n0 + half * 64 + colL) * 32768 + m0 + mseg * 8) = v;
        }
    }
}

// ---------------------------------------------------------------------------
// Single scan kernel, carry-free (warm-up compose: prod f over 128 t < e^-20).
// v2: all 12 gate loads + 8 warm-up loads hoisted upfront (latency overlap),
// fp16 output-staging LDS (16 KB, bank-clean), 1 h8 LDS-write per channel,
// h2 readout with 2 t-rows per thread.
// ---------------------------------------------------------------------------
__global__ __launch_bounds__(256)
void qrnn_scan(const _Float16* __restrict__ gT, float* __restrict__ out)
{
    __shared__ _Float16 oc[16 * 512];   // 16 KB: [channel][t]

    const int wv = threadIdx.x >> 6;
    const int l  = threadIdx.x & 63;
    const int tc  = blockIdx.x & 7;           // time chunk 0..7
    const int cg  = (blockIdx.x >> 3) & 15;   // channel group 0..15
    const int dir = (blockIdx.x >> 7) & 1;
    const int b   = blockIdx.x >> 8;
    const int t0  = tc * 512;

    const bool haveWarm = (dir == 0) ? (tc > 0) : (tc < 7);
    const int tw0 = (dir == 0) ? (t0 - 128) : (t0 + 512);

    // ---- upfront loads: 4 channels x {z,f,o} h8 + warm-up h2 ----
    h8 z8[4], f8[4], o8[4];
    h2 zw[4], fw[4];
#pragma unroll
    for (int cc = 0; cc < 4; ++cc) {
        const int oo = cg * 16 + wv * 4 + cc;
        const size_t colz = (size_t)(dir * 256 + oo) * 32768 + (b << 12);
        z8[cc] = *(const h8*)(gT + colz + t0 + l * 8);
        f8[cc] = *(const h8*)(gT + (size_t)512 * 32768 + colz + t0 + l * 8);
        o8[cc] = *(const h8*)(gT + (size_t)1024 * 32768 + colz + t0 + l * 8);
        if (haveWarm) {
            zw[cc] = *(const h2*)(gT + colz + tw0 + l * 2);
            fw[cc] = *(const h2*)(gT + (size_t)512 * 32768 + colz + tw0 + l * 2);
        }
    }

#pragma unroll
    for (int cc = 0; cc < 4; ++cc) {
        const int chl = wv * 4 + cc;

        // ---- warm-up: compose 128 preceding t (scan order) -> cinit ----
        float cinit = 0.0f;
        if (haveWarm) {
            float A = 1.0f, Bv = 0.0f;
            if (dir == 0) {
#pragma unroll
                for (int k = 0; k < 2; ++k) {
                    float f = fast_sigmoid((float)fw[cc][k]);
                    float g = (1.0f - f) * fast_tanh((float)zw[cc][k]);
                    Bv = f * Bv + g; A *= f;
                }
            } else {
#pragma unroll
                for (int k = 1; k >= 0; --k) {
                    float f = fast_sigmoid((float)fw[cc][k]);
                    float g = (1.0f - f) * fast_tanh((float)zw[cc][k]);
                    Bv = f * Bv + g; A *= f;
                }
            }
#pragma unroll
            for (int d = 1; d < 64; d <<= 1) {
                float Ao = __shfl_xor(A, d);
                float Bo = __shfl_xor(Bv, d);
                bool selfFirst = ((l & d) == 0);
                if (dir == 1) selfFirst = !selfFirst;
                if (selfFirst) { Bv = Ao * Bv + Bo; A = A * Ao; }
                else           { Bv = A * Bo + Bv; A = A * Ao; }
            }
            cinit = Bv;
        }

        // ---- local 8-step compose ----
        float fa[8], ga[8];
        float A = 1.0f, Bv = 0.0f;
        if (dir == 0) {
#pragma unroll
            for (int k = 0; k < 8; ++k) {
                fa[k] = fast_sigmoid((float)f8[cc][k]);
                ga[k] = (1.0f - fa[k]) * fast_tanh((float)z8[cc][k]);
                Bv = fa[k] * Bv + ga[k]; A *= fa[k];
            }
        } else {
#pragma unroll
            for (int k = 7; k >= 0; --k) {
                fa[k] = fast_sigmoid((float)f8[cc][k]);
                ga[k] = (1.0f - fa[k]) * fast_tanh((float)z8[cc][k]);
                Bv = fa[k] * Bv + ga[k]; A *= fa[k];
            }
        }

        // ---- wave-level exclusive scan ----
        float Ae, Be;
        if (dir == 0) {
#pragma unroll
            for (int d = 1; d < 64; d <<= 1) {
                float Ao = __shfl_up(A, d);
                float Bo = __shfl_up(Bv, d);
                if (l >= d) { Bv = A * Bo + Bv; A = A * Ao; }
            }
            Ae = __shfl_up(A, 1); Be = __shfl_up(Bv, 1);
            if (l == 0) { Ae = 1.0f; Be = 0.0f; }
        } else {
#pragma unroll
            for (int d = 1; d < 64; d <<= 1) {
                float Ao = __shfl_down(A, d);
                float Bo = __shfl_down(Bv, d);
                if (l + d < 64) { Bv = A * Bo + Bv; A = A * Ao; }
            }
            Ae = __shfl_down(A, 1); Be = __shfl_down(Bv, 1);
            if (l == 63) { Ae = 1.0f; Be = 0.0f; }
        }

        // ---- replay + output gate -> one h8 LDS write ----
        float s = Ae * cinit + Be;
        h8 res;
        if (dir == 0) {
#pragma unroll
            for (int k = 0; k < 8; ++k) {
                s = fa[k] * s + ga[k];
                res[k] = (_Float16)(fast_sigmoid((float)o8[cc][k]) * s);
            }
        } else {
#pragma unroll
            for (int k = 7; k >= 0; --k) {
                s = fa[k] * s + ga[k];
                res[k] = (_Float16)(fast_sigmoid((float)o8[cc][k]) * s);
            }
        }
        *(h8*)&oc[chl * 512 + l * 8] = res;
    }
    __syncthreads();

    // ---- readout: thread = 2 consecutive t rows, 64B per row ----
    const int t2 = threadIdx.x * 2;
    float r0[16], r1[16];
#pragma unroll
    for (int ch = 0; ch < 16; ++ch) {
        h2 v = *(const h2*)&oc[ch * 512 + t2];
        r0[ch] = (float)v[0];
        r1[ch] = (float)v[1];
    }
    const size_t row0 = (size_t)((b << 12) + t0 + t2);
    float* po0 = out + row0 * 512 + dir * 256 + cg * 16;
    float* po1 = po0 + 512;
    *(float4*)(po0)      = make_float4(r0[0], r0[1], r0[2], r0[3]);
    *(float4*)(po0 + 4)  = make_float4(r0[4], r0[5], r0[6], r0[7]);
    *(float4*)(po0 + 8)  = make_float4(r0[8], r0[9], r0[10], r0[11]);
    *(float4*)(po0 + 12) = make_float4(r0[12], r0[13], r0[14], r0[15]);
    *(float4*)(po1)      = make_float4(r1[0], r1[1], r1[2], r1[3]);
    *(float4*)(po1 + 4)  = make_float4(r1[4], r1[5], r1[6], r1[7]);
    *(float4*)(po1 + 8)  = make_float4(r1[8], r1[9], r1[10], r1[11]);
    *(float4*)(po1 + 12) = make_float4(r1[12], r1[13], r1[14], r1[15]);
}

// ---------------------------------------------------------------------------
extern "C" void kernel_launch(void* const* d_in, const int* in_sizes, int n_in,
                              void* d_out, int out_size, void* d_ws, size_t ws_size,
                              hipStream_t stream)
{
    const float* x    = (const float*)d_in[0];   // (8,4096,256) fp32
    const float* W    = (const float*)d_in[1];   // (1536,512)  fp32
    const float* bias = (const float*)d_in[2];   // (1536,)     fp32
    float* out = (float*)d_out;                  // (8,4096,512) fp32

    char* ws = (char*)d_ws;
    size_t off = 0;
    __hip_bfloat16* xb = (__hip_bfloat16*)(ws + off); off += (size_t)M_DIM * I_DIM * 2;
    __hip_bfloat16* Wb = (__hip_bfloat16*)(ws + off); off += (size_t)N_DIM * K_DIM * 2;
    _Float16* gT = (_Float16*)(ws + off); off += (size_t)N_DIM * M_DIM * 2;   // 100.7 MB
    unsigned short* zeroPage = (unsigned short*)(ws + off); off += 128;

    const int ncvt = NX4 + NW4;
    cvt_all<<<dim3((ncvt + 255) / 256), dim3(256), 0, stream>>>(
        x, W, (unsigned short*)xb, (unsigned short*)Wb, zeroPage);

    qrnn_gemm<<<dim3(256 * 12), dim3(256), 0, stream>>>(xb, Wb, bias, gT,
                                                        (const __hip_bfloat16*)zeroPage);

    qrnn_scan<<<dim3(B_DIM * 2 * 16 * 8), dim3(256), 0, stream>>>(gT, out);
}

// Round 9
// 195.053 us; speedup vs baseline: 1.0301x; 1.0301x over previous
//
#include <hip/hip_runtime.h>
#include <hip/hip_bf16.h>
#include <stdint.h>

// Problem constants
#define B_DIM 8
#define S_DIM 4096
#define I_DIM 256
#define M_DIM (B_DIM * S_DIM)   // 32768 rows
#define N_DIM 1536              // 6*OUT gate columns
#define K_DIM 512               // WINDOW*I

// GEMM tiling
#define TM 128
#define TN 128
#define BK 64
#define LT_STRIDE 136           // fp16 m-stride of epilogue transpose chunk (pad 8)

#define NX4 ((M_DIM * I_DIM) / 4)
#define NW4 ((N_DIM * K_DIM) / 4)

typedef __attribute__((ext_vector_type(8))) short bf16x8;
typedef __attribute__((ext_vector_type(4))) float f32x4;
typedef _Float16 h2 __attribute__((ext_vector_type(2)));
typedef _Float16 h4 __attribute__((ext_vector_type(4)));
typedef _Float16 h8 __attribute__((ext_vector_type(8)));

typedef const void __attribute__((address_space(1)))* gas_ptr;
typedef void __attribute__((address_space(3)))* las_ptr;

__device__ __forceinline__ void gload_lds16(const void* g, void* l) {
    __builtin_amdgcn_global_load_lds((gas_ptr)(uintptr_t)g, (las_ptr)(uintptr_t)l, 16, 0, 0);
}

__device__ __forceinline__ float fast_sigmoid(float x) {
    return 1.0f / (1.0f + __expf(-x));
}
__device__ __forceinline__ float fast_tanh(float x) {
    float ax = fabsf(x);
    float e = __expf(-2.0f * ax);
    float t = (1.0f - e) / (1.0f + e);
    return copysignf(t, x);
}

__device__ __forceinline__ unsigned short f2bf(float f) {
    uint32_t u = __float_as_uint(f);
    uint32_t r = (u + 0x7FFFu + ((u >> 16) & 1u)) >> 16;
    return (unsigned short)r;
}

// ---------------------------------------------------------------------------
// Single conversion kernel: x -> bf16, W -> bf16, zero page.
// ---------------------------------------------------------------------------
__global__ __launch_bounds__(256)
void cvt_all(const float* __restrict__ x, const float* __restrict__ W,
             unsigned short* __restrict__ xb, unsigned short* __restrict__ Wb,
             unsigned short* __restrict__ zp)
{
    int i = blockIdx.x * 256 + threadIdx.x;
    if (blockIdx.x == 0 && threadIdx.x < 64) zp[threadIdx.x] = 0;
    if (i < NX4) {
        float4 v = ((const float4*)x)[i];
        ushort4 o;
        o.x = f2bf(v.x); o.y = f2bf(v.y); o.z = f2bf(v.z); o.w = f2bf(v.w);
        ((ushort4*)xb)[i] = o;
    } else if (i < NX4 + NW4) {
        int j = i - NX4;
        float4 v = ((const float4*)W)[j];
        ushort4 o;
        o.x = f2bf(v.x); o.y = f2bf(v.y); o.z = f2bf(v.z); o.w = f2bf(v.w);
        ((ushort4*)Wb)[j] = o;
    }
}

// ---------------------------------------------------------------------------
// Windowed GEMM + bias -> PRE-ACTIVATION fp16, TRANSPOSED gT[col][m].
// Block remap (XCD-aware): assume round-robin block->XCD (idx&7). Each XCD
// gets a contiguous band of 32 tileM; within the band tileN is FAST-varying,
// so the 12 blocks sharing an A-tile run back-to-back on ONE XCD -> the
// A-tile lives in that XCD's L2 across all 12 uses (R8 FETCH was 4x of x).
// Epilogue: LDS transpose in two 64-col halves reusing the 32 KB staging LDS.
// A[m][k] = (k<256) ? x[b, s-1, k] (0 if s==0) : x[b, s, k-256]
// ---------------------------------------------------------------------------
__global__ __launch_bounds__(256, 2)
void qrnn_gemm(const __hip_bfloat16* __restrict__ x,
               const __hip_bfloat16* __restrict__ W,
               const float* __restrict__ bias,
               _Float16* __restrict__ gT,
               const __hip_bfloat16* __restrict__ zeroPage)
{
    __shared__ __hip_bfloat16 smem[TM * BK + TN * BK];   // 32 KB
    __hip_bfloat16* lA = smem;
    __hip_bfloat16* lB = smem + TM * BK;
    _Float16* tsp = (_Float16*)smem;                     // transpose chunk alias

    const int tid = threadIdx.x;
    const int w = tid >> 6;
    const int l = tid & 63;

    // XCD-aware tile mapping (perf heuristic only; any mapping is correct)
    const int xcd  = blockIdx.x & 7;
    const int slot = blockIdx.x >> 3;        // 0..383
    const int tileN = slot % 12;             // FAST within XCD band
    const int tileM = xcd * 32 + slot / 12;  // 0..255
    const int m0 = tileM * TM;
    const int n0 = tileN * TN;
    const int bIdx = m0 >> 12;
    const int sBase = m0 & 4095;

    const int c8 = (l & 7) ^ ((l >> 3) & 7);
    const int rowInP = w * 8 + (l >> 3);

    const int la = l & 15, lq = l >> 4;
    const int wm = w >> 1, wn = w & 1;

    f32x4 acc[4][4] = {};

    for (int kt = 0; kt < K_DIM / BK; ++kt) {
        __syncthreads();
        const int kcol = kt * 64 + c8 * 8;
#pragma unroll
        for (int p = 0; p < 4; ++p) {
            const int r = p * 32 + rowInP;
            const int srow = sBase + r;
            const __hip_bfloat16* srcA;
            if (kcol < 256) {
                srcA = (srow == 0) ? zeroPage
                     : x + ((size_t)((bIdx << 12) + srow - 1) * 256 + kcol);
            } else {
                srcA = x + ((size_t)((bIdx << 12) + srow) * 256 + (kcol - 256));
            }
            gload_lds16(srcA, &lA[p * 2048 + w * 512]);
            gload_lds16(W + ((size_t)(n0 + r) * 512 + kcol), &lB[p * 2048 + w * 512]);
        }
        __syncthreads();

#pragma unroll
        for (int kk = 0; kk < 2; ++kk) {
            bf16x8 af[4], bfr[4];
#pragma unroll
            for (int i = 0; i < 4; ++i) {
                const int ra = wm * 64 + i * 16 + la;
                const int ch = (kk * 4 + lq) ^ (ra & 7);
                af[i] = *(const bf16x8*)&lA[ra * 64 + ch * 8];
            }
#pragma unroll
            for (int j = 0; j < 4; ++j) {
                const int rb = wn * 64 + j * 16 + la;
                const int ch = (kk * 4 + lq) ^ (rb & 7);
                bfr[j] = *(const bf16x8*)&lB[rb * 64 + ch * 8];
            }
#pragma unroll
            for (int i = 0; i < 4; ++i)
#pragma unroll
                for (int j = 0; j < 4; ++j)
                    acc[i][j] = __builtin_amdgcn_mfma_f32_16x16x32_bf16(
                        af[i], bfr[j], acc[i][j], 0, 0, 0);
        }
    }

    // ---- epilogue: two 64-column halves through a 17.4 KB LDS chunk ----
    const int grp = tid >> 3;    // 0..31
    const int ln8 = tid & 7;
#pragma unroll
    for (int half = 0; half < 2; ++half) {
        __syncthreads();   // protect LDS (staging for half 0, prev chunk for half 1)
        if (wn == half) {
#pragma unroll
            for (int j = 0; j < 4; ++j) {
                const int colL = j * 16 + la;                // 0..63 in this half
                const float bv = bias[n0 + half * 64 + colL];
                _Float16* base = tsp + colL * LT_STRIDE + wm * 64 + lq * 4;
#pragma unroll
                for (int i = 0; i < 4; ++i) {
                    h4 hv;
#pragma unroll
                    for (int rr = 0; rr < 4; ++rr)
                        hv[rr] = (_Float16)(acc[i][j][rr] + bv);
                    *(h4*)(base + i * 16) = hv;
                }
            }
        }
        __syncthreads();
        // all 256 threads stream: 8 consecutive lanes = one column's 128B run
#pragma unroll
        for (int it = 0; it < 4; ++it) {
            const int colL = grp + 32 * (it & 1);            // 0..63
            const int mseg = ln8 + 8 * (it >> 1);            // 0..15
            h8 v = *(const h8*)(tsp + colL * LT_STRIDE + mseg * 8);
            *(h8*)(gT + (size_t)(n0 + half * 64 + colL) * 32768 + m0 + mseg * 8) = v;
        }
    }
}

// ---------------------------------------------------------------------------
// Single scan kernel, carry-free (warm-up compose: prod f over 128 t < e^-20).
// All 12 gate loads + 8 warm-up loads hoisted upfront, fp16 output-staging
// LDS (16 KB, bank-clean), h2 readout with 2 t-rows per thread.
// ---------------------------------------------------------------------------
__global__ __launch_bounds__(256)
void qrnn_scan(const _Float16* __restrict__ gT, float* __restrict__ out)
{
    __shared__ _Float16 oc[16 * 512];   // 16 KB: [channel][t]

    const int wv = threadIdx.x >> 6;
    const int l  = threadIdx.x & 63;
    const int tc  = blockIdx.x & 7;           // time chunk 0..7
    const int cg  = (blockIdx.x >> 3) & 15;   // channel group 0..15
    const int dir = (blockIdx.x >> 7) & 1;
    const int b   = blockIdx.x >> 8;
    const int t0  = tc * 512;

    const bool haveWarm = (dir == 0) ? (tc > 0) : (tc < 7);
    const int tw0 = (dir == 0) ? (t0 - 128) : (t0 + 512);

    // ---- upfront loads: 4 channels x {z,f,o} h8 + warm-up h2 ----
    h8 z8[4], f8[4], o8[4];
    h2 zw[4], fw[4];
#pragma unroll
    for (int cc = 0; cc < 4; ++cc) {
        const int oo = cg * 16 + wv * 4 + cc;
        const size_t colz = (size_t)(dir * 256 + oo) * 32768 + (b << 12);
        z8[cc] = *(const h8*)(gT + colz + t0 + l * 8);
        f8[cc] = *(const h8*)(gT + (size_t)512 * 32768 + colz + t0 + l * 8);
        o8[cc] = *(const h8*)(gT + (size_t)1024 * 32768 + colz + t0 + l * 8);
        if (haveWarm) {
            zw[cc] = *(const h2*)(gT + colz + tw0 + l * 2);
            fw[cc] = *(const h2*)(gT + (size_t)512 * 32768 + colz + tw0 + l * 2);
        }
    }

#pragma unroll
    for (int cc = 0; cc < 4; ++cc) {
        const int chl = wv * 4 + cc;

        // ---- warm-up: compose 128 preceding t (scan order) -> cinit ----
        float cinit = 0.0f;
        if (haveWarm) {
            float A = 1.0f, Bv = 0.0f;
            if (dir == 0) {
#pragma unroll
                for (int k = 0; k < 2; ++k) {
                    float f = fast_sigmoid((float)fw[cc][k]);
                    float g = (1.0f - f) * fast_tanh((float)zw[cc][k]);
                    Bv = f * Bv + g; A *= f;
                }
            } else {
#pragma unroll
                for (int k = 1; k >= 0; --k) {
                    float f = fast_sigmoid((float)fw[cc][k]);
                    float g = (1.0f - f) * fast_tanh((float)zw[cc][k]);
                    Bv = f * Bv + g; A *= f;
                }
            }
#pragma unroll
            for (int d = 1; d < 64; d <<= 1) {
                float Ao = __shfl_xor(A, d);
                float Bo = __shfl_xor(Bv, d);
                bool selfFirst = ((l & d) == 0);
                if (dir == 1) selfFirst = !selfFirst;
                if (selfFirst) { Bv = Ao * Bv + Bo; A = A * Ao; }
                else           { Bv = A * Bo + Bv; A = A * Ao; }
            }
            cinit = Bv;
        }

        // ---- local 8-step compose ----
        float fa[8], ga[8];
        float A = 1.0f, Bv = 0.0f;
        if (dir == 0) {
#pragma unroll
            for (int k = 0; k < 8; ++k) {
                fa[k] = fast_sigmoid((float)f8[cc][k]);
                ga[k] = (1.0f - fa[k]) * fast_tanh((float)z8[cc][k]);
                Bv = fa[k] * Bv + ga[k]; A *= fa[k];
            }
        } else {
#pragma unroll
            for (int k = 7; k >= 0; --k) {
                fa[k] = fast_sigmoid((float)f8[cc][k]);
                ga[k] = (1.0f - fa[k]) * fast_tanh((float)z8[cc][k]);
                Bv = fa[k] * Bv + ga[k]; A *= fa[k];
            }
        }

        // ---- wave-level exclusive scan ----
        float Ae, Be;
        if (dir == 0) {
#pragma unroll
            for (int d = 1; d < 64; d <<= 1) {
                float Ao = __shfl_up(A, d);
                float Bo = __shfl_up(Bv, d);
                if (l >= d) { Bv = A * Bo + Bv; A = A * Ao; }
            }
            Ae = __shfl_up(A, 1); Be = __shfl_up(Bv, 1);
            if (l == 0) { Ae = 1.0f; Be = 0.0f; }
        } else {
#pragma unroll
            for (int d = 1; d < 64; d <<= 1) {
                float Ao = __shfl_down(A, d);
                float Bo = __shfl_down(Bv, d);
                if (l + d < 64) { Bv = A * Bo + Bv; A = A * Ao; }
            }
            Ae = __shfl_down(A, 1); Be = __shfl_down(Bv, 1);
            if (l == 63) { Ae = 1.0f; Be = 0.0f; }
        }

        // ---- replay + output gate -> one h8 LDS write ----
        float s = Ae * cinit + Be;
        h8 res;
        if (dir == 0) {
#pragma unroll
            for (int k = 0; k < 8; ++k) {
                s = fa[k] * s + ga[k];
                res[k] = (_Float16)(fast_sigmoid((float)o8[cc][k]) * s);
            }
        } else {
#pragma unroll
            for (int k = 7; k >= 0; --k) {
                s = fa[k] * s + ga[k];
                res[k] = (_Float16)(fast_sigmoid((float)o8[cc][k]) * s);
            }
        }
        *(h8*)&oc[chl * 512 + l * 8] = res;
    }
    __syncthreads();

    // ---- readout: thread = 2 consecutive t rows, 64B per row ----
    const int t2 = threadIdx.x * 2;
    float r0[16], r1[16];
#pragma unroll
    for (int ch = 0; ch < 16; ++ch) {
        h2 v = *(const h2*)&oc[ch * 512 + t2];
        r0[ch] = (float)v[0];
        r1[ch] = (float)v[1];
    }
    const size_t row0 = (size_t)((b << 12) + t0 + t2);
    float* po0 = out + row0 * 512 + dir * 256 + cg * 16;
    float* po1 = po0 + 512;
    *(float4*)(po0)      = make_float4(r0[0], r0[1], r0[2], r0[3]);
    *(float4*)(po0 + 4)  = make_float4(r0[4], r0[5], r0[6], r0[7]);
    *(float4*)(po0 + 8)  = make_float4(r0[8], r0[9], r0[10], r0[11]);
    *(float4*)(po0 + 12) = make_float4(r0[12], r0[13], r0[14], r0[15]);
    *(float4*)(po1)      = make_float4(r1[0], r1[1], r1[2], r1[3]);
    *(float4*)(po1 + 4)  = make_float4(r1[4], r1[5], r1[6], r1[7]);
    *(float4*)(po1 + 8)  = make_float4(r1[8], r1[9], r1[10], r1[11]);
    *(float4*)(po1 + 12) = make_float4(r1[12], r1[13], r1[14], r1[15]);
}

// ---------------------------------------------------------------------------
extern "C" void kernel_launch(void* const* d_in, const int* in_sizes, int n_in,
                              void* d_out, int out_size, void* d_ws, size_t ws_size,
                              hipStream_t stream)
{
    const float* x    = (const float*)d_in[0];   // (8,4096,256) fp32
    const float* W    = (const float*)d_in[1];   // (1536,512)  fp32
    const float* bias = (const float*)d_in[2];   // (1536,)     fp32
    float* out = (float*)d_out;                  // (8,4096,512) fp32

    char* ws = (char*)d_ws;
    size_t off = 0;
    __hip_bfloat16* xb = (__hip_bfloat16*)(ws + off); off += (size_t)M_DIM * I_DIM * 2;
    __hip_bfloat16* Wb = (__hip_bfloat16*)(ws + off); off += (size_t)N_DIM * K_DIM * 2;
    _Float16* gT = (_Float16*)(ws + off); off += (size_t)N_DIM * M_DIM * 2;   // 100.7 MB
    unsigned short* zeroPage = (unsigned short*)(ws + off); off += 128;

    const int ncvt = NX4 + NW4;
    cvt_all<<<dim3((ncvt + 255) / 256), dim3(256), 0, stream>>>(
        x, W, (unsigned short*)xb, (unsigned short*)Wb, zeroPage);

    qrnn_gemm<<<dim3(256 * 12), dim3(256), 0, stream>>>(xb, Wb, bias, gT,
                                                        (const __hip_bfloat16*)zeroPage);

    qrnn_scan<<<dim3(B_DIM * 2 * 16 * 8), dim3(256), 0, stream>>>(gT, out);
}